// Round 9
// baseline (207.143 us; speedup 1.0000x reference)
//
#include <hip/hip_runtime.h>
#include <cfloat>
#include <stdint.h>

// z: [32768, 32] fp32 rows; emb: [8192, 32] fp32 codes.
// Outputs (fp32, concat): quantized[1048576] | vq_loss | commit_loss | idx[32768]
//
// Strategy (R13): bf16 MFMA filter + exact fp32 re-check.
//  R12->R13: register diet BY GEOMETRY. Evidence: natural compiles carry
//  8 A-frags + 32-float max state -> ~92 arch VGPR + MFMA acc > 128 total
//  -> 2 waves/SIMD (occ 18%); every launch_bounds cap attempt spills to
//  64 VGPR + 45-65MB scratch. Fix: split ROWS across waves. Block =
//  128 rows x ALL 8192 codes, 8 waves = 2 row-groups x 4 code-slices;
//  each wave: 4 A-frags (16 regs) x 2048 codes -> ~64 total regs ->
//  6-8 waves/SIMD naturally, no cap needed. Full-codebook coverage per
//  block restores GLOBAL thresholds (tight candidates, final stays fast).
#define NROW   32768
#define KCODES 8192
#define CDIM   32
#define OUT_Q    0
#define OUT_LOSS 1048576
#define OUT_IDX  1048578
#define HALF_EPS 1e-4f
#define MAXCAND  32

typedef short bf8_t __attribute__((ext_vector_type(8)));   // 8 bf16 (4 VGPRs)
typedef float f32x4 __attribute__((ext_vector_type(4)));

__device__ __forceinline__ unsigned short f2bf(float f) {  // RNE float->bf16
  unsigned int u = __float_as_uint(f);
  return (unsigned short)((u + 0x7FFFu + ((u >> 16) & 1u)) >> 16);
}
// Order-preserving float<->uint transform (for atomicMax on signed floats).
__device__ __forceinline__ unsigned int xf(float f) {
  unsigned int u = __float_as_uint(f);
  return u ^ (unsigned int)(((int)u >> 31) | 0x80000000);
}
__device__ __forceinline__ float unxf(unsigned int k) {
  unsigned int u = (k & 0x80000000u) ? (k ^ 0x80000000u) : ~k;
  return __uint_as_float(u);
}

// ---------------------------------------------------------------------------
// Prep: z/emb -> bf16 copies; enorm (bit-identical chain); init ccnt/losses.
// grid 128x256 = 32768 threads.
// ---------------------------------------------------------------------------
__global__ __launch_bounds__(256) void vq_prep(
    const float* __restrict__ z, const float* __restrict__ emb,
    unsigned short* __restrict__ zh, unsigned short* __restrict__ eh,
    float* __restrict__ enorm, int* __restrict__ ccnt,
    float* __restrict__ out) {
  const int t = blockIdx.x * 256 + threadIdx.x;  // 0..32767
  {
    const float4* z4 = (const float4*)(z + (size_t)t * CDIM);
    unsigned int w[16];
#pragma unroll
    for (int j = 0; j < 8; ++j) {
      float4 v = z4[j];
      w[2 * j]     = (unsigned int)f2bf(v.x) | ((unsigned int)f2bf(v.y) << 16);
      w[2 * j + 1] = (unsigned int)f2bf(v.z) | ((unsigned int)f2bf(v.w) << 16);
    }
    uint4* o = (uint4*)(zh + (size_t)t * CDIM);
#pragma unroll
    for (int j = 0; j < 4; ++j)
      o[j] = make_uint4(w[4 * j], w[4 * j + 1], w[4 * j + 2], w[4 * j + 3]);
  }
  if (t < KCODES) {
    const float4* e4 = (const float4*)(emb + (size_t)t * CDIM);
    float s = 0.f;
    unsigned int w[16];
#pragma unroll
    for (int j = 0; j < 8; ++j) {
      float4 v = e4[j];
      s += v.x * v.x + v.y * v.y + v.z * v.z + v.w * v.w;  // exact enorm chain
      w[2 * j]     = (unsigned int)f2bf(v.x) | ((unsigned int)f2bf(v.y) << 16);
      w[2 * j + 1] = (unsigned int)f2bf(v.z) | ((unsigned int)f2bf(v.w) << 16);
    }
    enorm[t] = s;
    uint4* o = (uint4*)(eh + (size_t)t * CDIM);
#pragma unroll
    for (int j = 0; j < 4; ++j)
      o[j] = make_uint4(w[4 * j], w[4 * j + 1], w[4 * j + 2], w[4 * j + 3]);
  }
  ccnt[t] = 0;
  if (t < 2) out[OUT_LOSS + t] = 0.f;
}

// ---------------------------------------------------------------------------
// Sweep: block = 128 rows x ALL 8192 codes. 512 threads = 8 waves =
// 2 row-groups (64 rows) x 4 code-slices (2048 codes = 128 tiles of 16).
// Wave wid: rgrp = wid>>2, kslice = wid&3.
// A-frag f (f<4): A[m=lane&15][k=quad*8+j] = zh[rbase+rgrp*64+f*16+m][k]
// B-frag:   B[k][n=lane&15] = eh[code][k]
// C/D:      lane holds D[row=quad*4+i][col=lane&15], i=0..3.
//  pass 1: running max in regs (2-tile groups, v_max3 fold) -> LDS
//          atomic_max -> col-reduce -> rowmax over FULL codebook (global).
//  pass 2: bitwise-identical recompute; emit codes with d >= rowmax-eps.
// Per-wave regs ~64 (a16+mx16+b8+d8+misc) -> 6-8 waves/SIMD naturally.
// grid = 256 blocks.
// ---------------------------------------------------------------------------
__global__ __launch_bounds__(512) void vq_sweep(
    const unsigned short* __restrict__ zh, const unsigned short* __restrict__ eh,
    int* __restrict__ ccnt, int* __restrict__ cand) {
  __shared__ unsigned int smax[128][16];  // [row][col] partial maxes (xf)
  __shared__ unsigned int rowmax[128];    // per-row global max (xf)
  const int wid = threadIdx.x >> 6, lane = threadIdx.x & 63;
  const int quad = lane >> 4, col = lane & 15;
  const int rgrp = wid >> 2, kslice = wid & 3;
  const int rbase = blockIdx.x * 128;
  const int rowoff = rgrp * 64;           // this wave's 64-row group
  const int kbase = kslice * 2048;        // this wave's 2048-code slice

  for (int i = threadIdx.x; i < 128 * 16; i += 512)
    ((unsigned int*)smax)[i] = 0u;  // xf-space -inf

  bf8_t a[4];
#pragma unroll
  for (int f = 0; f < 4; ++f)
    a[f] = *(const bf8_t*)(zh +
        (size_t)(rbase + rowoff + f * 16 + col) * CDIM + quad * 8);

  float mx[4][4];
#pragma unroll
  for (int f = 0; f < 4; ++f)
#pragma unroll
    for (int i = 0; i < 4; ++i) mx[f][i] = -FLT_MAX;

  const bf8_t* ep = (const bf8_t*)(eh + ((size_t)kbase + col) * CDIM + quad * 8);
  const f32x4 zero = {0.f, 0.f, 0.f, 0.f};
  __syncthreads();  // smax init visible before any ds atomic

  // ---- pass 1: per-row max over this wave's 2048 codes ----
  for (int tt = 0; tt < 128; tt += 2) {
    bf8_t b0 = ep[(size_t)(tt + 0) * 64];  // +16 codes * 64B per tile
    bf8_t b1 = ep[(size_t)(tt + 1) * 64];
#pragma unroll
    for (int f = 0; f < 4; ++f) {
      f32x4 d0 = __builtin_amdgcn_mfma_f32_16x16x32_bf16(a[f], b0, zero, 0, 0, 0);
      f32x4 d1 = __builtin_amdgcn_mfma_f32_16x16x32_bf16(a[f], b1, zero, 0, 0, 0);
#pragma unroll
      for (int i = 0; i < 4; ++i)  // fmax(fmax(d0,d1),mx) -> v_max3_f32
        mx[f][i] = fmaxf(fmaxf(d0[i], d1[i]), mx[f][i]);
    }
  }
#pragma unroll
  for (int f = 0; f < 4; ++f)
#pragma unroll
    for (int i = 0; i < 4; ++i)
      atomicMax(&smax[rowoff + f * 16 + quad * 4 + i][col], xf(mx[f][i]));
  __syncthreads();
  if (threadIdx.x < 128) {  // reduce 16 col-partials per row -> GLOBAL max
    unsigned int m = 0u;
#pragma unroll
    for (int c = 0; c < 16; ++c) {
      unsigned int v = smax[threadIdx.x][c];
      if (v > m) m = v;
    }
    rowmax[threadIdx.x] = m;
  }
  __syncthreads();

  float th[4][4], thmin[4];
#pragma unroll
  for (int f = 0; f < 4; ++f) {
#pragma unroll
    for (int i = 0; i < 4; ++i)
      th[f][i] = unxf(rowmax[rowoff + f * 16 + quad * 4 + i]) - HALF_EPS;
    thmin[f] = fminf(fminf(th[f][0], th[f][1]), fminf(th[f][2], th[f][3]));
  }

  // ---- pass 2: candidate emission (d bitwise identical to pass 1) ----
#define FINE_TILE(dj, j)                                                     \
  {                                                                          \
    const int code = code0 + (j) * 16;                                       \
    _Pragma("unroll") for (int i = 0; i < 4; ++i) {                          \
      if (dj[i] >= th[f][i]) {                                               \
        int r = rbase + rowoff + f * 16 + quad * 4 + i;                      \
        int s = atomicAdd(&ccnt[r], 1);                                      \
        if (s < MAXCAND) cand[(size_t)r * MAXCAND + s] = code;               \
      }                                                                      \
    }                                                                        \
  }

  for (int tt = 0; tt < 128; tt += 2) {
    bf8_t b0 = ep[(size_t)(tt + 0) * 64];
    bf8_t b1 = ep[(size_t)(tt + 1) * 64];
    const int code0 = kbase + tt * 16 + col;
#pragma unroll
    for (int f = 0; f < 4; ++f) {
      f32x4 d0 = __builtin_amdgcn_mfma_f32_16x16x32_bf16(a[f], b0, zero, 0, 0, 0);
      f32x4 d1 = __builtin_amdgcn_mfma_f32_16x16x32_bf16(a[f], b1, zero, 0, 0, 0);
      // coarse gate over the 8 values (no false negatives: any dj[i] >=
      // th[f][i] implies md >= dj[i] >= th[f][i] >= thmin[f])
      float m0 = fmaxf(fmaxf(d0[0], d0[1]), fmaxf(d0[2], d0[3]));
      float m1 = fmaxf(fmaxf(d1[0], d1[1]), fmaxf(d1[2], d1[3]));
      float md = fmaxf(m0, m1);
      if (md >= thmin[f]) {
        FINE_TILE(d0, 0)
        FINE_TILE(d1, 1)
      }
    }
  }
#undef FINE_TILE
}

// ---------------------------------------------------------------------------
// Finalize: one thread per row, exact fp32 re-eval of candidates.
// Overflow rows (> MAXCAND, ~never with global thresholds) handled by a
// wave-cooperative exact scan: 64 lanes split the 8192 codes; shfl_xor
// argmin reduce, (dist,idx) lex tie-break (== reference first-min).
// grid 128x256.
// ---------------------------------------------------------------------------
__global__ __launch_bounds__(256) void vq_final(
    const float* __restrict__ z, const float* __restrict__ emb,
    const float* __restrict__ enorm, const int* __restrict__ ccnt,
    const int* __restrict__ cand, float* __restrict__ out) {
  const int r = blockIdx.x * 256 + threadIdx.x;
  const int lane = threadIdx.x & 63;

  float zr[CDIM];
  const float4* z4 = (const float4*)(z + (size_t)r * CDIM);
#pragma unroll
  for (int j = 0; j < 8; ++j) {
    float4 v = z4[j];
    zr[4 * j + 0] = v.x; zr[4 * j + 1] = v.y;
    zr[4 * j + 2] = v.z; zr[4 * j + 3] = v.w;
  }
  float znorm = 0.f;
#pragma unroll
  for (int j = 0; j < CDIM; ++j) znorm = fmaf(zr[j], zr[j], znorm);

  const int n = ccnt[r];
  float best = FLT_MAX;
  int bidx = KCODES;
  if (n <= MAXCAND) {
    for (int j = 0; j < n; ++j) {
      int k = cand[(size_t)r * MAXCAND + j];
      const float* ek = emb + (size_t)k * CDIM;
      float dot = 0.f;
#pragma unroll
      for (int q = 0; q < CDIM; ++q) dot = fmaf(zr[q], ek[q], dot);
      float s = fmaf(-2.f, dot, znorm) + enorm[k];
      if (s < best || (s == best && k < bidx)) { best = s; bidx = k; }
    }
  }

  // Wave-cooperative exact scan for overflow rows (rare).
  unsigned long long ovf = __ballot(n > MAXCAND);
  while (ovf) {
    const int src = __ffsll((long long)ovf) - 1;
    ovf &= ovf - 1;
    const int rr = __shfl(r, src, 64);
    float zs[CDIM];
    const float4* zz4 = (const float4*)(z + (size_t)rr * CDIM);
#pragma unroll
    for (int j = 0; j < 8; ++j) {
      float4 v = zz4[j];  // uniform address -> broadcast
      zs[4 * j + 0] = v.x; zs[4 * j + 1] = v.y;
      zs[4 * j + 2] = v.z; zs[4 * j + 3] = v.w;
    }
    float zn = 0.f;
#pragma unroll
    for (int j = 0; j < CDIM; ++j) zn = fmaf(zs[j], zs[j], zn);
    float b = FLT_MAX;
    int bi = KCODES;
    for (int k = lane; k < KCODES; k += 64) {
      const float* ek = emb + (size_t)k * CDIM;
      float dot = 0.f;
#pragma unroll
      for (int q = 0; q < CDIM; ++q) dot = fmaf(zs[q], ek[q], dot);
      float s = fmaf(-2.f, dot, zn) + enorm[k];
      if (s < b) { b = s; bi = k; }  // ascending k + strict < => lowest k
    }
#pragma unroll
    for (int off = 1; off < 64; off <<= 1) {
      float ob = __shfl_xor(b, off, 64);
      int oi = __shfl_xor(bi, off, 64);
      if (ob < b || (ob == b && oi < bi)) { b = ob; bi = oi; }
    }
    if (lane == src) { best = b; bidx = bi; }
  }

  const float4* q4 = (const float4*)(emb + (size_t)bidx * CDIM);
  float4* o4 = (float4*)(out + OUT_Q + (size_t)r * CDIM);
  float lsum = 0.f;
#pragma unroll
  for (int j = 0; j < 8; ++j) {
    float4 q = q4[j];
    float dx = zr[4 * j + 0] - q.x, dy = zr[4 * j + 1] - q.y;
    float dz = zr[4 * j + 2] - q.z, dw = zr[4 * j + 3] - q.w;
    lsum += dx * dx + dy * dy + dz * dz + dw * dw;
    o4[j] = q;
  }
  out[OUT_IDX + r] = (float)bidx;

#pragma unroll
  for (int off = 32; off > 0; off >>= 1) lsum += __shfl_down(lsum, off, 64);
  if ((threadIdx.x & 63) == 0) {
    float v = lsum * (1.0f / (float)(NROW * CDIM));
    atomicAdd(out + OUT_LOSS + 0, v);
    atomicAdd(out + OUT_LOSS + 1, v);
  }
}

// ---------------------------------------------------------------------------
extern "C" void kernel_launch(void* const* d_in, const int* in_sizes, int n_in,
                              void* d_out, int out_size, void* d_ws,
                              size_t ws_size, hipStream_t stream) {
  const float* z = (const float*)d_in[0];
  const float* emb = (const float*)d_in[1];
  float* out = (float*)d_out;

  // ws: enorm 32KB | zh 2MB | eh 512KB | ccnt 128KB | cand 4MB
  float* enorm = (float*)d_ws;
  unsigned short* zh = (unsigned short*)(enorm + KCODES);
  unsigned short* eh = zh + (size_t)NROW * CDIM;
  int* ccnt = (int*)(eh + (size_t)KCODES * CDIM);
  int* cand = ccnt + NROW;

  vq_prep<<<NROW / 256, 256, 0, stream>>>(z, emb, zh, eh, enorm, ccnt, out);
  vq_sweep<<<NROW / 128, 512, 0, stream>>>(zh, eh, ccnt, cand);
  vq_final<<<NROW / 256, 256, 0, stream>>>(z, emb, enorm, ccnt, cand, out);
}

// Round 10
// 163.678 us; speedup vs baseline: 1.2655x; 1.2655x over previous
//
#include <hip/hip_runtime.h>
#include <cfloat>
#include <stdint.h>

// z: [32768, 32] fp32 rows; emb: [8192, 32] fp32 codes.
// Outputs (fp32, concat): quantized[1048576] | vq_loss | commit_loss | idx[32768]
//
// Strategy (R14): bf16 MFMA filter + exact fp32 re-check, TWO-PHASE sweep.
//  R13 post-mortem: occupancy = min(grid-waves/CU, reg cap). R13's diet
//  body (52 VGPR) fixed regs but its 2048-wave grid capped occupancy at
//  8 waves/CU (19%). R14: 4x the waves. Split the fused sweep back into
//  max + cand kernels (R5 structure) with the diet body:
//   - vq_sweep_max : 2048 blocks x 4 waves; wave = 64 rows (4 frags) x
//     512 codes; reg max -> LDS -> one global atomicMax per row.
//   - vq_sweep_cand: same geometry; reads converged GLOBAL rowmax
//     (kernel boundary) -> full-codebook-tight thresholds -> ~1-4
//     candidates/row; barrier-free inner loop, zero smax LDS.
//  8192 waves -> 32 waves/CU potential at ~52 VGPR. prep/final on
//  256 blocks x 128 thr so all CUs participate. Coop-scan overflow
//  fallback retained in final (never expected with global thresholds).
#define NROW   32768
#define KCODES 8192
#define CDIM   32
#define OUT_Q    0
#define OUT_LOSS 1048576
#define OUT_IDX  1048578
#define HALF_EPS 1e-4f
#define MAXCAND  32

typedef short bf8_t __attribute__((ext_vector_type(8)));   // 8 bf16 (4 VGPRs)
typedef float f32x4 __attribute__((ext_vector_type(4)));

__device__ __forceinline__ unsigned short f2bf(float f) {  // RNE float->bf16
  unsigned int u = __float_as_uint(f);
  return (unsigned short)((u + 0x7FFFu + ((u >> 16) & 1u)) >> 16);
}
// Order-preserving float<->uint transform (for atomicMax on signed floats).
__device__ __forceinline__ unsigned int xf(float f) {
  unsigned int u = __float_as_uint(f);
  return u ^ (unsigned int)(((int)u >> 31) | 0x80000000);
}
__device__ __forceinline__ float unxf(unsigned int k) {
  unsigned int u = (k & 0x80000000u) ? (k ^ 0x80000000u) : ~k;
  return __uint_as_float(u);
}

// ---------------------------------------------------------------------------
// Prep: z/emb -> bf16 copies; enorm (bit-identical chain); init mmax/ccnt/
// losses.  grid 256x128 = 32768 threads (all CUs).
// ---------------------------------------------------------------------------
__global__ __launch_bounds__(128) void vq_prep(
    const float* __restrict__ z, const float* __restrict__ emb,
    unsigned short* __restrict__ zh, unsigned short* __restrict__ eh,
    float* __restrict__ enorm, unsigned int* __restrict__ mmax,
    int* __restrict__ ccnt, float* __restrict__ out) {
  const int t = blockIdx.x * 128 + threadIdx.x;  // 0..32767
  {
    const float4* z4 = (const float4*)(z + (size_t)t * CDIM);
    unsigned int w[16];
#pragma unroll
    for (int j = 0; j < 8; ++j) {
      float4 v = z4[j];
      w[2 * j]     = (unsigned int)f2bf(v.x) | ((unsigned int)f2bf(v.y) << 16);
      w[2 * j + 1] = (unsigned int)f2bf(v.z) | ((unsigned int)f2bf(v.w) << 16);
    }
    uint4* o = (uint4*)(zh + (size_t)t * CDIM);
#pragma unroll
    for (int j = 0; j < 4; ++j)
      o[j] = make_uint4(w[4 * j], w[4 * j + 1], w[4 * j + 2], w[4 * j + 3]);
  }
  if (t < KCODES) {
    const float4* e4 = (const float4*)(emb + (size_t)t * CDIM);
    float s = 0.f;
    unsigned int w[16];
#pragma unroll
    for (int j = 0; j < 8; ++j) {
      float4 v = e4[j];
      s += v.x * v.x + v.y * v.y + v.z * v.z + v.w * v.w;  // exact enorm chain
      w[2 * j]     = (unsigned int)f2bf(v.x) | ((unsigned int)f2bf(v.y) << 16);
      w[2 * j + 1] = (unsigned int)f2bf(v.z) | ((unsigned int)f2bf(v.w) << 16);
    }
    enorm[t] = s;
    uint4* o = (uint4*)(eh + (size_t)t * CDIM);
#pragma unroll
    for (int j = 0; j < 4; ++j)
      o[j] = make_uint4(w[4 * j], w[4 * j + 1], w[4 * j + 2], w[4 * j + 3]);
  }
  mmax[t] = 0u;   // transformed -inf
  ccnt[t] = 0;
  if (t < 2) out[OUT_LOSS + t] = 0.f;
}

// ---------------------------------------------------------------------------
// Sweep phase 1: per-row global max of dot~.
// grid = 2048 blocks x 256 thr (4 waves). Block = 64 rows x 2048 codes:
// rowgroup = bid>>2 (64 rows), kquarter = bid&3; wave wid covers codes
// [kquarter*2048 + wid*512, +512) = 32 tiles of 16.
// A-frag f (f<4): A[m=lane&15][k=quad*8+j] = zh[rbase+f*16+m][k]
// B-frag:   B[k][n=lane&15] = eh[code][k]
// C/D:      lane holds D[row=quad*4+i][col=lane&15], i=0..3.
// Reg max (2-tile groups, v_max3 fold) -> LDS atomicMax -> col-reduce ->
// ONE global atomicMax per row. ~52 VGPR -> up to 8 waves/SIMD.
// ---------------------------------------------------------------------------
__global__ __launch_bounds__(256) void vq_sweep_max(
    const unsigned short* __restrict__ zh, const unsigned short* __restrict__ eh,
    unsigned int* __restrict__ mmax) {
  __shared__ unsigned int smax[64][16];  // [row][col] partial maxes (xf)
  const int wid = threadIdx.x >> 6, lane = threadIdx.x & 63;
  const int quad = lane >> 4, col = lane & 15;
  const int rbase = (blockIdx.x >> 2) * 64;
  const int kbase = (blockIdx.x & 3) * 2048 + wid * 512;

  for (int i = threadIdx.x; i < 64 * 16; i += 256)
    ((unsigned int*)smax)[i] = 0u;  // xf-space -inf

  bf8_t a[4];
#pragma unroll
  for (int f = 0; f < 4; ++f)
    a[f] = *(const bf8_t*)(zh + (size_t)(rbase + f * 16 + col) * CDIM + quad * 8);

  float mx[4][4];
#pragma unroll
  for (int f = 0; f < 4; ++f)
#pragma unroll
    for (int i = 0; i < 4; ++i) mx[f][i] = -FLT_MAX;

  const bf8_t* ep = (const bf8_t*)(eh + ((size_t)kbase + col) * CDIM + quad * 8);
  const f32x4 zero = {0.f, 0.f, 0.f, 0.f};
  __syncthreads();  // smax init visible before LDS atomics

  for (int tt = 0; tt < 32; tt += 2) {
    bf8_t b0 = ep[(size_t)(tt + 0) * 64];  // +16 codes * 64B per tile
    bf8_t b1 = ep[(size_t)(tt + 1) * 64];
#pragma unroll
    for (int f = 0; f < 4; ++f) {
      f32x4 d0 = __builtin_amdgcn_mfma_f32_16x16x32_bf16(a[f], b0, zero, 0, 0, 0);
      f32x4 d1 = __builtin_amdgcn_mfma_f32_16x16x32_bf16(a[f], b1, zero, 0, 0, 0);
#pragma unroll
      for (int i = 0; i < 4; ++i)  // fmax(fmax(d0,d1),mx) -> v_max3_f32
        mx[f][i] = fmaxf(fmaxf(d0[i], d1[i]), mx[f][i]);
    }
  }
#pragma unroll
  for (int f = 0; f < 4; ++f)
#pragma unroll
    for (int i = 0; i < 4; ++i)
      atomicMax(&smax[f * 16 + quad * 4 + i][col], xf(mx[f][i]));
  __syncthreads();
  if (threadIdx.x < 64) {  // reduce 16 col-partials -> one global atomic/row
    unsigned int m = 0u;
#pragma unroll
    for (int c = 0; c < 16; ++c) {
      unsigned int v = smax[threadIdx.x][c];
      if (v > m) m = v;
    }
    atomicMax(&mmax[rbase + threadIdx.x], m);
  }
}

// ---------------------------------------------------------------------------
// Sweep phase 2: candidate emission. Same geometry as phase 1; recomputes
// the bitwise-identical dot~ and emits codes with d >= global_rowmax - eps.
// The rowmax achiever passes (same bits) -> every row gets >= 1 candidate.
// Global thresholds -> ~1-4 candidates/row. Barrier-free inner loop.
// ---------------------------------------------------------------------------
__global__ __launch_bounds__(256) void vq_sweep_cand(
    const unsigned short* __restrict__ zh, const unsigned short* __restrict__ eh,
    const unsigned int* __restrict__ mmax, int* __restrict__ ccnt,
    int* __restrict__ cand) {
  __shared__ float rowth[64];  // per-row threshold stage
  const int wid = threadIdx.x >> 6, lane = threadIdx.x & 63;
  const int quad = lane >> 4, col = lane & 15;
  const int rbase = (blockIdx.x >> 2) * 64;
  const int kbase = (blockIdx.x & 3) * 2048 + wid * 512;

  if (threadIdx.x < 64)
    rowth[threadIdx.x] = unxf(mmax[rbase + threadIdx.x]) - HALF_EPS;

  bf8_t a[4];
#pragma unroll
  for (int f = 0; f < 4; ++f)
    a[f] = *(const bf8_t*)(zh + (size_t)(rbase + f * 16 + col) * CDIM + quad * 8);

  const bf8_t* ep = (const bf8_t*)(eh + ((size_t)kbase + col) * CDIM + quad * 8);
  const f32x4 zero = {0.f, 0.f, 0.f, 0.f};
  __syncthreads();  // rowth visible

  float th[4][4], thmin[4];
#pragma unroll
  for (int f = 0; f < 4; ++f) {
#pragma unroll
    for (int i = 0; i < 4; ++i)
      th[f][i] = rowth[f * 16 + quad * 4 + i];
    thmin[f] = fminf(fminf(th[f][0], th[f][1]), fminf(th[f][2], th[f][3]));
  }

#define FINE_TILE(dj, j)                                                     \
  {                                                                          \
    const int code = code0 + (j) * 16;                                       \
    _Pragma("unroll") for (int i = 0; i < 4; ++i) {                          \
      if (dj[i] >= th[f][i]) {                                               \
        int r = rbase + f * 16 + quad * 4 + i;                               \
        int s = atomicAdd(&ccnt[r], 1);                                      \
        if (s < MAXCAND) cand[(size_t)r * MAXCAND + s] = code;               \
      }                                                                      \
    }                                                                        \
  }

  for (int tt = 0; tt < 32; tt += 2) {
    bf8_t b0 = ep[(size_t)(tt + 0) * 64];
    bf8_t b1 = ep[(size_t)(tt + 1) * 64];
    const int code0 = kbase + tt * 16 + col;
#pragma unroll
    for (int f = 0; f < 4; ++f) {
      f32x4 d0 = __builtin_amdgcn_mfma_f32_16x16x32_bf16(a[f], b0, zero, 0, 0, 0);
      f32x4 d1 = __builtin_amdgcn_mfma_f32_16x16x32_bf16(a[f], b1, zero, 0, 0, 0);
      // coarse gate (no false negatives: any dj[i] >= th[f][i] implies
      // md >= dj[i] >= th[f][i] >= thmin[f])
      float m0 = fmaxf(fmaxf(d0[0], d0[1]), fmaxf(d0[2], d0[3]));
      float m1 = fmaxf(fmaxf(d1[0], d1[1]), fmaxf(d1[2], d1[3]));
      float md = fmaxf(m0, m1);
      if (md >= thmin[f]) {
        FINE_TILE(d0, 0)
        FINE_TILE(d1, 1)
      }
    }
  }
#undef FINE_TILE
}

// ---------------------------------------------------------------------------
// Finalize: one thread per row, exact fp32 re-eval of candidates.
// Overflow rows (> MAXCAND, ~never with global thresholds) handled by a
// wave-cooperative exact scan: 64 lanes split the 8192 codes; shfl_xor
// argmin reduce, (dist,idx) lex tie-break (== reference first-min).
// grid 256x128 (all CUs).
// ---------------------------------------------------------------------------
__global__ __launch_bounds__(128) void vq_final(
    const float* __restrict__ z, const float* __restrict__ emb,
    const float* __restrict__ enorm, const int* __restrict__ ccnt,
    const int* __restrict__ cand, float* __restrict__ out) {
  const int r = blockIdx.x * 128 + threadIdx.x;
  const int lane = threadIdx.x & 63;

  float zr[CDIM];
  const float4* z4 = (const float4*)(z + (size_t)r * CDIM);
#pragma unroll
  for (int j = 0; j < 8; ++j) {
    float4 v = z4[j];
    zr[4 * j + 0] = v.x; zr[4 * j + 1] = v.y;
    zr[4 * j + 2] = v.z; zr[4 * j + 3] = v.w;
  }
  float znorm = 0.f;
#pragma unroll
  for (int j = 0; j < CDIM; ++j) znorm = fmaf(zr[j], zr[j], znorm);

  const int n = ccnt[r];
  float best = FLT_MAX;
  int bidx = KCODES;
  if (n <= MAXCAND) {
    for (int j = 0; j < n; ++j) {
      int k = cand[(size_t)r * MAXCAND + j];
      const float* ek = emb + (size_t)k * CDIM;
      float dot = 0.f;
#pragma unroll
      for (int q = 0; q < CDIM; ++q) dot = fmaf(zr[q], ek[q], dot);
      float s = fmaf(-2.f, dot, znorm) + enorm[k];
      if (s < best || (s == best && k < bidx)) { best = s; bidx = k; }
    }
  }

  // Wave-cooperative exact scan for overflow rows (rare).
  unsigned long long ovf = __ballot(n > MAXCAND);
  while (ovf) {
    const int src = __ffsll((long long)ovf) - 1;
    ovf &= ovf - 1;
    const int rr = __shfl(r, src, 64);
    float zs[CDIM];
    const float4* zz4 = (const float4*)(z + (size_t)rr * CDIM);
#pragma unroll
    for (int j = 0; j < 8; ++j) {
      float4 v = zz4[j];  // uniform address -> broadcast
      zs[4 * j + 0] = v.x; zs[4 * j + 1] = v.y;
      zs[4 * j + 2] = v.z; zs[4 * j + 3] = v.w;
    }
    float zn = 0.f;
#pragma unroll
    for (int j = 0; j < CDIM; ++j) zn = fmaf(zs[j], zs[j], zn);
    float b = FLT_MAX;
    int bi = KCODES;
    for (int k = lane; k < KCODES; k += 64) {
      const float* ek = emb + (size_t)k * CDIM;
      float dot = 0.f;
#pragma unroll
      for (int q = 0; q < CDIM; ++q) dot = fmaf(zs[q], ek[q], dot);
      float s = fmaf(-2.f, dot, zn) + enorm[k];
      if (s < b) { b = s; bi = k; }  // ascending k + strict < => lowest k
    }
#pragma unroll
    for (int off = 1; off < 64; off <<= 1) {
      float ob = __shfl_xor(b, off, 64);
      int oi = __shfl_xor(bi, off, 64);
      if (ob < b || (ob == b && oi < bi)) { b = ob; bi = oi; }
    }
    if (lane == src) { best = b; bidx = bi; }
  }

  const float4* q4 = (const float4*)(emb + (size_t)bidx * CDIM);
  float4* o4 = (float4*)(out + OUT_Q + (size_t)r * CDIM);
  float lsum = 0.f;
#pragma unroll
  for (int j = 0; j < 8; ++j) {
    float4 q = q4[j];
    float dx = zr[4 * j + 0] - q.x, dy = zr[4 * j + 1] - q.y;
    float dz = zr[4 * j + 2] - q.z, dw = zr[4 * j + 3] - q.w;
    lsum += dx * dx + dy * dy + dz * dz + dw * dw;
    o4[j] = q;
  }
  out[OUT_IDX + r] = (float)bidx;

#pragma unroll
  for (int off = 32; off > 0; off >>= 1) lsum += __shfl_down(lsum, off, 64);
  if ((threadIdx.x & 63) == 0) {
    float v = lsum * (1.0f / (float)(NROW * CDIM));
    atomicAdd(out + OUT_LOSS + 0, v);
    atomicAdd(out + OUT_LOSS + 1, v);
  }
}

// ---------------------------------------------------------------------------
extern "C" void kernel_launch(void* const* d_in, const int* in_sizes, int n_in,
                              void* d_out, int out_size, void* d_ws,
                              size_t ws_size, hipStream_t stream) {
  const float* z = (const float*)d_in[0];
  const float* emb = (const float*)d_in[1];
  float* out = (float*)d_out;

  // ws: enorm 32KB | zh 2MB | eh 512KB | mmax 128KB | ccnt 128KB | cand 4MB
  float* enorm = (float*)d_ws;
  unsigned short* zh = (unsigned short*)(enorm + KCODES);
  unsigned short* eh = zh + (size_t)NROW * CDIM;
  unsigned int* mmax = (unsigned int*)(eh + (size_t)KCODES * CDIM);
  int* ccnt = (int*)(mmax + NROW);
  int* cand = ccnt + NROW;

  vq_prep<<<NROW / 128, 128, 0, stream>>>(z, emb, zh, eh, enorm, mmax, ccnt, out);
  vq_sweep_max<<<(NROW / 64) * 4, 256, 0, stream>>>(zh, eh, mmax);
  vq_sweep_cand<<<(NROW / 64) * 4, 256, 0, stream>>>(zh, eh, mmax, ccnt, cand);
  vq_final<<<NROW / 128, 128, 0, stream>>>(z, emb, enorm, ccnt, cand, out);
}